// Round 9
// baseline (2723.129 us; speedup 1.0000x reference)
//
#include <hip/hip_runtime.h>
#include <math.h>

#define M_ROWS 2048
#define N_KEYS 65536
#define DKK 512
#define DVV 512
#define KTOP 32
#define NSPLIT 16
#define NRANGE (N_KEYS / NSPLIT)   // 4096
#define BM 128
#define BN 256
#define MBLKS (M_ROWS / BM)        // 16
#define NTILES (NRANGE / BN)       // 16
#define KSTEPS (DKK / 32)          // 16
#define TOT (NTILES * KSTEPS)      // 256
#define KKEEP 48
#define KSTR 49
#define CAP 24
#define CSTR 25
#define TILE_E 4096                // elems per 128x32 tile

typedef _Float16 f16x8 __attribute__((ext_vector_type(8)));
typedef float f32x4 __attribute__((ext_vector_type(4)));
typedef unsigned long long u64t;

// ===================== FAST PATH =====================

// (score desc, idx asc) order as single u64 descending compare
__device__ __forceinline__ u64t packSI(float s, int idx) {
  unsigned u = __float_as_uint(s);
  u = (u & 0x80000000u) ? ~u : (u | 0x80000000u);
  return ((u64t)u << 32) | (unsigned)(~idx);
}
__device__ __forceinline__ float unpackS(u64t p) {
  unsigned u = (unsigned)(p >> 32);
  return __uint_as_float((u & 0x80000000u) ? (u ^ 0x80000000u) : ~u);
}
#define PNEG_INF ((((u64t)0x007FFFFFu) << 32) | 0x80000000u)   // pack(-inf, 0x7fffffff)

// norm + f16 hi/lo split + tiled+swizzled layout:
// arr[tile][ks][rr*32 + (oct^((rr>>1)&3))*8]
__global__ void __launch_bounds__(256) norm_split_kernel(
    const float* __restrict__ q, const float* __restrict__ keys,
    _Float16* __restrict__ QhT, _Float16* __restrict__ QlT,
    _Float16* __restrict__ KhT, _Float16* __restrict__ KlT) {
  const int gw = (blockIdx.x * 256 + threadIdx.x) >> 6;
  const int lane = threadIdx.x & 63;
  const float* row; _Float16 *oh, *ol; int rr;
  if (gw < M_ROWS) {
    row = q + (size_t)gw * DKK; rr = gw & 127;
    const size_t tb = (size_t)(gw >> 7) * 16 * TILE_E;
    oh = QhT + tb; ol = QlT + tb;
  } else {
    const int n = gw - M_ROWS;
    if (n >= N_KEYS) return;
    row = keys + (size_t)n * DKK; rr = n & 127;
    const size_t tb = (size_t)(n >> 7) * 16 * TILE_E;
    oh = KhT + tb; ol = KlT + tb;
  }
  const float4 a = *(const float4*)&row[lane * 8];
  const float4 b = *(const float4*)&row[lane * 8 + 4];
  float s = a.x*a.x + a.y*a.y + a.z*a.z + a.w*a.w
          + b.x*b.x + b.y*b.y + b.z*b.z + b.w*b.w;
#pragma unroll
  for (int off = 32; off; off >>= 1) s += __shfl_xor(s, off);
  const float inv = 1.0f / fmaxf(sqrtf(s), 1e-12f);

  f16x8 h, l;
  const float e[8] = {a.x, a.y, a.z, a.w, b.x, b.y, b.z, b.w};
#pragma unroll
  for (int j = 0; j < 8; ++j) {
    const float y = e[j] * inv;
    h[j] = (_Float16)y;
    l[j] = (_Float16)(y - (float)h[j]);
  }
  const int ks = lane >> 2, oct = lane & 3;
  const int po = oct ^ ((rr >> 1) & 3);
  const size_t off = (size_t)ks * TILE_E + rr * 32 + po * 8;
  *(f16x8*)&oh[off] = h;
  *(f16x8*)&ol[off] = l;
}

__device__ __forceinline__ void insert48(u64t* tp, u64t v) {
  if (v <= tp[KKEEP - 1]) return;
  int p = 0;
  while (p < KKEEP && tp[p] > v) ++p;
  for (int qq = KKEEP - 1; qq > p; --qq) tp[qq] = tp[qq - 1];
  tp[p] = v;
}

__device__ __forceinline__ void gll16(const _Float16* g, _Float16* l) {
  __builtin_amdgcn_global_load_lds(
      (const __attribute__((address_space(1))) void*)g,
      (__attribute__((address_space(3))) void*)l, 16, 0, 0);
}

// inline-asm LDS read (invisible to waitcnt pass; rule #18 handled by caller)
__device__ __forceinline__ f16x8 ldsr128(const _Float16* p) {
  f16x8 d;
  const __attribute__((address_space(3))) _Float16* lp =
      (const __attribute__((address_space(3))) _Float16*)p;
  asm volatile("ds_read_b128 %0, %1" : "=v"(d) : "v"(lp));
  return d;
}

#define SB0() __builtin_amdgcn_sched_barrier(0)
#define LBAR() do {                                                    \
  SB0(); asm volatile("s_waitcnt lgkmcnt(0)" ::: "memory");            \
  SB0(); __builtin_amdgcn_s_barrier(); SB0();                          \
} while (0)

// stage step S: Qh 128x32 (1 gll) + Kh 256x32 (2 gll)
#define STAGE(B, S) do {                                               \
  const int _ct = (S) >> 4, _ks = (S) & 15;                            \
  gll16(QhT + qtb + (size_t)_ks * TILE_E, &sQh[B][ldsA]);              \
  const size_t _k0 = ktb + ((size_t)(_ct * 2) * 16 + _ks) * TILE_E;    \
  gll16(KhT + _k0, &sKh[B][ldsA]);                                     \
  gll16(KhT + _k0 + 16 * TILE_E, &sKh[B][4096 + ldsA]);                \
} while (0)

__global__ void __launch_bounds__(512, 2) pass1_kernel(
    const _Float16* __restrict__ QhT, const _Float16* __restrict__ KhT,
    u64t* __restrict__ plist) {
  __shared__ __attribute__((aligned(16))) _Float16 sQh[3][TILE_E];       // 24 KB
  __shared__ __attribute__((aligned(16))) _Float16 sKh[3][2 * TILE_E];   // 48 KB
  __shared__ u64t topP[BM * KSTR];    // 50 KB
  __shared__ u64t candP[BM * CSTR];   // 25.6 KB
  __shared__ float mSf[BM];
  __shared__ int cnt[BM];
  __shared__ int sOver;

  const int tid  = threadIdx.x;
  const int lane = tid & 63;
  const int w    = tid >> 6;           // 8 waves
  const int wr   = w >> 1, wc = w & 1; // wave tile 32 x 128
  const int cl   = lane & 15;
  const int g    = lane >> 4;
  const int g4   = g * 4;

  // XCD-chunked bijective swizzle (256 blocks = 8 XCD * 32)
  const int lin   = (int)(blockIdx.x + gridDim.x * blockIdx.y);
  const int virt  = (lin & 7) * 32 + (lin >> 3);
  const int mblk  = virt & (MBLKS - 1);
  const int split = virt >> 4;
  const int qbase  = mblk * BM;
  const int nbase0 = split * NRANGE;

  const int ldsA = tid * 8;
  const size_t qtb = (size_t)mblk * 16 * TILE_E + ldsA;
  const size_t ktb = (size_t)(split * (NRANGE / 128)) * 16 * TILE_E + ldsA;

  int offA[2], offB[8];
#pragma unroll
  for (int mi = 0; mi < 2; ++mi) {
    const int r = wr * 32 + mi * 16 + cl;
    offA[mi] = r * 32 + (g ^ ((r >> 1) & 3)) * 8;
  }
#pragma unroll
  for (int ni = 0; ni < 8; ++ni) {
    const int c = wc * 128 + ni * 16 + cl;
    const int crr = c & 127;
    offB[ni] = (c >> 7) * TILE_E + crr * 32 + (g ^ ((crr >> 1) & 3)) * 8;
  }

  if (tid < BM) {
    mSf[tid] = -INFINITY; cnt[tid] = 0;
#pragma unroll
    for (int j = 0; j < KKEEP; ++j) topP[tid * KSTR + j] = PNEG_INF;
  }
  if (tid == 0) sOver = 0;

  STAGE(0, 0);
  STAGE(1, 1);
  int rb = 0;

  for (int ct = 0; ct < NTILES; ++ct) {
    const int n0 = nbase0 + ct * BN;
    f32x4 acc[2][8];
#pragma unroll
    for (int mi = 0; mi < 2; ++mi)
#pragma unroll
      for (int ni = 0; ni < 8; ++ni) acc[mi][ni] = (f32x4)0.0f;

    for (int ks = 0; ks < KSTEPS; ++ks) {
      const int s = ct * KSTEPS + ks;
      if (s == TOT - 1) {
        SB0(); asm volatile("s_waitcnt vmcnt(0)" ::: "memory"); SB0();
      } else {
        SB0(); asm volatile("s_waitcnt vmcnt(3)" ::: "memory"); SB0();
      }
      __builtin_amdgcn_s_barrier();
      SB0();

      if (s + 2 < TOT) {
        int rb2 = rb + 2; if (rb2 >= 3) rb2 -= 3;
        STAGE(rb2, s + 2);
      }
      SB0();

      f16x8 Ah0 = ldsr128(&sQh[rb][offA[0]]);
      f16x8 Ah1 = ldsr128(&sQh[rb][offA[1]]);
      f16x8 Bh[8];
#pragma unroll
      for (int ni = 0; ni < 8; ++ni) Bh[ni] = ldsr128(&sKh[rb][offB[ni]]);
      asm volatile("s_waitcnt lgkmcnt(0)" ::: "memory");
      SB0();

      __builtin_amdgcn_s_setprio(1);
#pragma unroll
      for (int ni = 0; ni < 8; ++ni) {
        acc[0][ni] = __builtin_amdgcn_mfma_f32_16x16x32_f16(Ah0, Bh[ni], acc[0][ni], 0, 0, 0);
        acc[1][ni] = __builtin_amdgcn_mfma_f32_16x16x32_f16(Ah1, Bh[ni], acc[1][ni], 0, 0, 0);
      }
      __builtin_amdgcn_s_setprio(0);

      ++rb; if (rb >= 3) rb -= 3;
    }

    // -------- candidate scan (vmcnt NOT drained; stages keep flying) --------
    LBAR();
    float m[2][4];
#pragma unroll
    for (int mi = 0; mi < 2; ++mi) {
      const f32x4 mv = *(const f32x4*)&mSf[wr * 32 + mi * 16 + g4];
      m[mi][0] = mv[0]; m[mi][1] = mv[1]; m[mi][2] = mv[2]; m[mi][3] = mv[3];
    }
    u64t pend = 0ull;
#pragma unroll
    for (int mi = 0; mi < 2; ++mi)
#pragma unroll
      for (int ni = 0; ni < 8; ++ni)
#pragma unroll
        for (int j = 0; j < 4; ++j)
          if (acc[mi][ni][j] >= m[mi][j])
            pend |= 1ull << (mi * 32 + ni * 4 + j);

    for (;;) {
      if (pend) {
#pragma unroll
        for (int mi = 0; mi < 2; ++mi)
#pragma unroll
          for (int ni = 0; ni < 8; ++ni)
#pragma unroll
            for (int j = 0; j < 4; ++j) {
              const int bit = mi * 32 + ni * 4 + j;
              if (pend & (1ull << bit)) {
                const int r = wr * 32 + mi * 16 + g4 + j;
                const int t = atomicAdd(&cnt[r], 1);
                if (t < CAP) {
                  candP[r * CSTR + t] = packSI(acc[mi][ni][j], n0 + wc * 128 + ni * 16 + cl);
                  pend &= ~(1ull << bit);
                }
              }
            }
      }
      LBAR();
      if (tid < BM) {
        int nc = cnt[tid];
        if (nc > CAP) { sOver = 1; nc = CAP; }
        u64t* tp = &topP[tid * KSTR];
        for (int e = 0; e < nc; ++e) insert48(tp, candP[tid * CSTR + e]);
        mSf[tid] = unpackS(tp[KKEEP - 1]);
        cnt[tid] = 0;
      }
      LBAR();
      const int over = sOver;
      LBAR();
      if (tid == 0) sOver = 0;
      if (!over) break;
#pragma unroll
      for (int mi = 0; mi < 2; ++mi) {
        const f32x4 mv = *(const f32x4*)&mSf[wr * 32 + mi * 16 + g4];
        m[mi][0] = mv[0]; m[mi][1] = mv[1]; m[mi][2] = mv[2]; m[mi][3] = mv[3];
      }
      u64t keep = 0ull;
#pragma unroll
      for (int mi = 0; mi < 2; ++mi)
#pragma unroll
        for (int ni = 0; ni < 8; ++ni)
#pragma unroll
          for (int j = 0; j < 4; ++j) {
            const int bit = mi * 32 + ni * 4 + j;
            if ((pend & (1ull << bit)) && acc[mi][ni][j] >= m[mi][j])
              keep |= 1ull << bit;
          }
      pend = keep;
    }
  }

  if (tid < BM) {
    u64t* dst = &plist[((size_t)(qbase + tid) * NSPLIT + split) * KKEEP];
    for (int j = 0; j < KKEEP; ++j) dst[j] = topP[tid * KSTR + j];
  }
}

// pass 2: merge 16x48 1-term lists -> top-48; bit-exact 3-term re-score;
// exact sort; softmax; value gather.
__global__ void __launch_bounds__(256) pass2_kernel(
    const u64t* __restrict__ plist,
    const _Float16* __restrict__ QhT, const _Float16* __restrict__ QlT,
    const _Float16* __restrict__ KhT, const _Float16* __restrict__ KlT,
    const float* __restrict__ values,
    float* __restrict__ out_agg, float* __restrict__ out_attn, float* __restrict__ out_idx) {
  __shared__ u64t sel[KKEEP];
  __shared__ int selIdx[KKEEP];
  __shared__ float sEx[KKEEP];
  __shared__ u64t pEx[KKEEP];
  __shared__ int sIdx[KKEEP];
  __shared__ float sSc[KKEEP];
  __shared__ float attn_s[KTOP];

  const int row = blockIdx.x;
  const int tid = threadIdx.x;
  const int lane = tid & 63;
  const int w = tid >> 6;

  if (tid < 64) {
    int pos = 0;
    u64t v = 0;
    if (lane < NSPLIT) v = plist[((size_t)row * NSPLIT + lane) * KKEEP];
    for (int it = 0; it < KKEEP; ++it) {
      u64t wv = v; int wl = lane;
#pragma unroll
      for (int off = 32; off; off >>= 1) {
        const u64t ov = __shfl_xor(wv, off);
        const int ol = __shfl_xor(wl, off);
        if (ov > wv) { wv = ov; wl = ol; }
      }
      if (lane == 0) sel[it] = wv;
      if (lane == wl) {
        ++pos;
        v = (pos < KKEEP) ? plist[((size_t)row * NSPLIT + lane) * KKEEP + pos] : 0;
      }
    }
  }
  __syncthreads();
  if (tid < KKEEP) selIdx[tid] = (int)(~(unsigned)(sel[tid] & 0xffffffffull));
  __syncthreads();

  if (w < 3) {
    const int cl = lane & 15, g = lane >> 4;
    const int c = selIdx[w * 16 + cl];
    const int crr = c & 127;
    const int rr = row & 127;
    const size_t cb  = ((size_t)(c >> 7) * 16) * TILE_E + crr * 32 + (g ^ ((crr >> 1) & 3)) * 8;
    const size_t qb2 = ((size_t)(row >> 7) * 16) * TILE_E + rr * 32 + (g ^ ((rr >> 1) & 3)) * 8;
    f32x4 acc = (f32x4)0.0f;
    for (int ks = 0; ks < KSTEPS; ++ks) {
      const f16x8 Ah = *(const f16x8*)&QhT[qb2 + (size_t)ks * TILE_E];
      const f16x8 Al = *(const f16x8*)&QlT[qb2 + (size_t)ks * TILE_E];
      const f16x8 Bh = *(const f16x8*)&KhT[cb + (size_t)ks * TILE_E];
      const f16x8 Bl = *(const f16x8*)&KlT[cb + (size_t)ks * TILE_E];
      // same 3-term order as the fused kernel -> bit-identical scores
      acc = __builtin_amdgcn_mfma_f32_16x16x32_f16(Al, Bh, acc, 0, 0, 0);
      acc = __builtin_amdgcn_mfma_f32_16x16x32_f16(Ah, Bl, acc, 0, 0, 0);
      acc = __builtin_amdgcn_mfma_f32_16x16x32_f16(Ah, Bh, acc, 0, 0, 0);
    }
    if (g == 0) sEx[w * 16 + cl] = acc[0];
  }
  __syncthreads();
  if (tid < KKEEP) pEx[tid] = packSI(sEx[tid], selIdx[tid]);
  __syncthreads();
  if (tid < KKEEP) {
    const u64t me = pEx[tid];
    int rank = 0;
    for (int k = 0; k < KKEEP; ++k) rank += (pEx[k] > me);
    sIdx[rank] = selIdx[tid]; sSc[rank] = sEx[tid];
  }
  __syncthreads();
  if (tid < KTOP) {
    const float mm = sSc[0];
    const float e = expf((sSc[tid] - mm) * 10.0f);
    float tsum = e;
#pragma unroll
    for (int off = 16; off; off >>= 1) tsum += __shfl_xor(tsum, off);
    const float a = e / tsum;
    out_attn[(size_t)row * KTOP + tid] = a;
    out_idx [(size_t)row * KTOP + tid] = (float)sIdx[tid];
    attn_s[tid] = a;
  }
  __syncthreads();

  const int d = tid * 2;
  float2 accv = make_float2(0.0f, 0.0f);
  for (int j = 0; j < KTOP; ++j) {
    const float wg = attn_s[j];
    const float2 v2 = *(const float2*)&values[(size_t)sIdx[j] * DVV + d];
    accv.x = fmaf(wg, v2.x, accv.x);
    accv.y = fmaf(wg, v2.y, accv.y);
  }
  *(float2*)&out_agg[(size_t)row * DVV + d] = accv;
}

// ===================== FALLBACK (round-1, proven) =====================

#define QB 128
#define NB 128
#define KC 32
#define FNTILES (NRANGE / NB)
#define KCH (DKK / KC)
#define LDST 132

__global__ void __launch_bounds__(256) norm_kernel(
    const float* __restrict__ q, const float* __restrict__ keys,
    float* __restrict__ qn, float* __restrict__ kinv) {
  const int gw = (blockIdx.x * 256 + threadIdx.x) >> 6;
  const int lane = threadIdx.x & 63;
  if (gw < M_ROWS) {
    const float* row = q + (size_t)gw * DKK;
    float4 a = ((const float4*)row)[lane];
    float4 b = ((const float4*)row)[lane + 64];
    float s = a.x*a.x + a.y*a.y + a.z*a.z + a.w*a.w
            + b.x*b.x + b.y*b.y + b.z*b.z + b.w*b.w;
#pragma unroll
    for (int off = 32; off; off >>= 1) s += __shfl_xor(s, off);
    const float inv = 1.0f / fmaxf(sqrtf(s), 1e-12f);
    float* orow = qn + (size_t)gw * DKK;
    ((float4*)orow)[lane]      = make_float4(a.x*inv, a.y*inv, a.z*inv, a.w*inv);
    ((float4*)orow)[lane + 64] = make_float4(b.x*inv, b.y*inv, b.z*inv, b.w*inv);
  } else {
    const int n = gw - M_ROWS;
    if (n < N_KEYS) {
      const float* row = keys + (size_t)n * DKK;
      float4 a = ((const float4*)row)[lane];
      float4 b = ((const float4*)row)[lane + 64];
      float s = a.x*a.x + a.y*a.y + a.z*a.z + a.w*a.w
              + b.x*b.x + b.y*b.y + b.z*b.z + b.w*b.w;
#pragma unroll
      for (int off = 32; off; off >>= 1) s += __shfl_xor(s, off);
      if (lane == 0) kinv[n] = 1.0f / fmaxf(sqrtf(s), 1e-12f);
    }
  }
}

__device__ __forceinline__ void lds_wr_tile(float* dst, int k8, int r, float4 v, float scale) {
  dst[(k8 * 4 + 0) * LDST + r] = v.x * scale;
  dst[(k8 * 4 + 1) * LDST + r] = v.y * scale;
  dst[(k8 * 4 + 2) * LDST + r] = v.z * scale;
  dst[(k8 * 4 + 3) * LDST + r] = v.w * scale;
}

__global__ void __launch_bounds__(256, 1) score_topk_kernel(
    const float* __restrict__ qn, const float* __restrict__ keys,
    const float* __restrict__ kinv,
    float* __restrict__ pscore, int* __restrict__ pidx) {
  __shared__ float u[16896];
  __shared__ float topS[QB * KTOP];
  __shared__ int   topI[QB * KTOP];

  const int tid = threadIdx.x;
  const int tx = tid & 15, ty = tid >> 4;
  const int qbase = blockIdx.y * QB;
  const int nbase0 = blockIdx.x * NRANGE;

  for (int i = tid; i < QB * KTOP; i += 256) { topS[i] = -INFINITY; topI[i] = 0; }
  __syncthreads();

  for (int t = 0; t < FNTILES; ++t) {
    const int n0 = nbase0 + t * NB;
    float acc[8][8];
#pragma unroll
    for (int i = 0; i < 8; ++i)
#pragma unroll
      for (int j = 0; j < 8; ++j) acc[i][j] = 0.0f;

#pragma unroll
    for (int p = 0; p < 4; ++p) {
      const int id = tid + p * 256;
      const int r = id >> 3, k8 = id & 7;
      const float4 va = *(const float4*)&qn[(size_t)(qbase + r) * DKK + k8 * 4];
      const float4 vb = *(const float4*)&keys[(size_t)(n0 + r) * DKK + k8 * 4];
      const float kv = kinv[n0 + r];
      lds_wr_tile(u, k8, r, va, 1.0f);
      lds_wr_tile(u + 4224, k8, r, vb, kv);
    }
    __syncthreads();

    for (int kc = 0; kc < KCH; ++kc) {
      float4 pa[4], pb[4]; float pk[4];
      const bool pre = (kc + 1 < KCH);
      if (pre) {
#pragma unroll
        for (int p = 0; p < 4; ++p) {
          const int id = tid + p * 256;
          const int r = id >> 3, k8 = id & 7;
          pa[p] = *(const float4*)&qn[(size_t)(qbase + r) * DKK + (kc + 1) * KC + k8 * 4];
          pb[p] = *(const float4*)&keys[(size_t)(n0 + r) * DKK + (kc + 1) * KC + k8 * 4];
          pk[p] = kinv[n0 + r];
        }
      }
      const float* As = u + (kc & 1) * 8448;
      const float* Bs = As + 4224;
#pragma unroll 4
      for (int kk = 0; kk < KC; ++kk) {
        const float4 a0 = *(const float4*)&As[kk * LDST + ty * 4];
        const float4 a1 = *(const float4*)&As[kk * LDST + ty * 4 + 64];
        const float4 b0 = *(const float4*)&Bs[kk * LDST + tx * 4];
        const float4 b1 = *(const float4*)&Bs[kk * LDST + tx * 4 + 64];
        const float av[8] = {a0.x,a0.y,a0.z,a0.w,a1.x,a1.y,a1.z,a1.w};
        const float bv[8] = {b0.x,b0.y,b0.z,b0.w,b1.x,b1.y,b1.z,b1.w};
#pragma unroll
        for (int i = 0; i < 8; ++i)
#pragma unroll
          for (int j = 0; j < 8; ++j)
            acc[i][j] = fmaf(av[i], bv[j], acc[i][j]);
      }
      if (pre) {
        float* Ad = u + ((kc + 1) & 1) * 8448;
        float* Bd = Ad + 4224;
#pragma unroll
        for (int p = 0; p < 4; ++p) {
          const int id = tid + p * 256;
          const int r = id >> 3, k8 = id & 7;
          lds_wr_tile(Ad, k8, r, pa[p], 1.0f);
          lds_wr_tile(Bd, k8, r, pb[p], pk[p]);
        }
      }
      __syncthreads();
    }

#pragma unroll
    for (int ib = 0; ib < 2; ++ib)
#pragma unroll
      for (int i = 0; i < 4; ++i) {
        const int r = ty * 4 + i + ib * 64;
#pragma unroll
        for (int jb = 0; jb < 2; ++jb) {
          *(float4*)&u[r * LDST + tx * 4 + jb * 64] =
              make_float4(acc[ib*4+i][jb*4+0], acc[ib*4+i][jb*4+1],
                          acc[ib*4+i][jb*4+2], acc[ib*4+i][jb*4+3]);
        }
      }
    __syncthreads();

    if (tid < QB) {
      const int row = tid;
      float* tS = &topS[row * KTOP];
      int*   tI = &topI[row * KTOP];
      float mSv = tS[KTOP - 1]; int mIv = tI[KTOP - 1];
      for (int c4 = 0; c4 < NB / 4; ++c4) {
        const float4 v = *(const float4*)&u[row * LDST + c4 * 4];
#pragma unroll
        for (int wv = 0; wv < 4; ++wv) {
          const float s = (&v.x)[wv];
          const int idx = n0 + c4 * 4 + wv;
          if (s > mSv || (s == mSv && idx < mIv)) {
            int p = 0;
            while (p < KTOP && (tS[p] > s || (tS[p] == s && tI[p] < idx))) ++p;
            for (int qq = KTOP - 1; qq > p; --qq) { tS[qq] = tS[qq-1]; tI[qq] = tI[qq-1]; }
            tS[p] = s; tI[p] = idx;
            mSv = tS[KTOP - 1]; mIv = tI[KTOP - 1];
          }
        }
      }
    }
    __syncthreads();
  }

  if (tid < QB) {
    const size_t base = ((size_t)(qbase + tid) * NSPLIT + blockIdx.x) * KTOP;
    for (int j = 0; j < KTOP; ++j) {
      pscore[base + j] = topS[tid * KTOP + j];
      pidx[base + j]   = topI[tid * KTOP + j];
    }
  }
}

__global__ void __launch_bounds__(256) merge_kernel(
    const float* __restrict__ pscore, const int* __restrict__ pidx,
    const float* __restrict__ values,
    float* __restrict__ out_agg, float* __restrict__ out_attn, float* __restrict__ out_idx) {
  __shared__ float attn_s[KTOP];
  __shared__ int   sel_i[KTOP];
  const int row = blockIdx.x;
  const int tid = threadIdx.x;

  if (tid < 64) {
    const int lane = tid;
    const float* ps = pscore + (size_t)row * NSPLIT * KTOP;
    const int*   pi = pidx   + (size_t)row * NSPLIT * KTOP;
    int pos = 0;
    float s; int idx;
    if (lane < NSPLIT) { s = ps[lane * KTOP]; idx = pi[lane * KTOP]; }
    else { s = -INFINITY; idx = 0x7fffffff; }
    for (int it = 0; it < KTOP; ++it) {
      float wsv = s; int wi = idx; int wl = lane;
#pragma unroll
      for (int off = 32; off; off >>= 1) {
        const float os = __shfl_xor(wsv, off);
        const int   oi = __shfl_xor(wi, off);
        const int   ol = __shfl_xor(wl, off);
        if (os > wsv || (os == wsv && oi < wi)) { wsv = os; wi = oi; wl = ol; }
      }
      if (lane == 0) { attn_s[it] = wsv; sel_i[it] = wi; }
      if (lane == wl) {
        ++pos;
        if (pos < KTOP) { s = ps[lane * KTOP + pos]; idx = pi[lane * KTOP + pos]; }
        else { s = -INFINITY; idx = 0x7fffffff; }
      }
    }
  }
  __syncthreads();
  if (tid < KTOP) {
    const float mm = attn_s[0];
    const float e = expf((attn_s[tid] - mm) * 10.0f);
    float tsum = e;
#pragma unroll
    for (int off = 16; off; off >>= 1) tsum += __shfl_xor(tsum, off);
    const float a = e / tsum;
    out_attn[(size_t)row * KTOP + tid] = a;
    out_idx [(size_t)row * KTOP + tid] = (float)sel_i[tid];
    attn_s[tid] = a;
  }
  __syncthreads();

  const int d = tid * 2;
  float2 accv = make_float2(0.0f, 0.0f);
  for (int j = 0; j < KTOP; ++j) {
    const float wgt = attn_s[j];
    const float2 v = *(const float2*)&values[(size_t)sel_i[j] * DVV + d];
    accv.x = fmaf(wgt, v.x, accv.x);
    accv.y = fmaf(wgt, v.y, accv.y);
  }
  *(float2*)&out_agg[(size_t)row * DVV + d] = accv;
}

extern "C" void kernel_launch(void* const* d_in, const int* in_sizes, int n_in,
                              void* d_out, int out_size, void* d_ws, size_t ws_size,
                              hipStream_t stream) {
  const float* q      = (const float*)d_in[0];
  const float* keys   = (const float*)d_in[1];
  const float* values = (const float*)d_in[2];

  float* out      = (float*)d_out;
  float* out_agg  = out;
  float* out_attn = out + (size_t)M_ROWS * DVV;
  float* out_idx  = out_attn + (size_t)M_ROWS * KTOP;

  const size_t needFast =
      (size_t)M_ROWS * DKK * 2 * 2          // QhT,QlT
    + (size_t)N_KEYS * DKK * 2 * 2          // KhT,KlT
    + (size_t)M_ROWS * NSPLIT * KKEEP * 8;  // plist (u64)

  if (ws_size >= needFast) {
    _Float16* QhT = (_Float16*)d_ws;
    _Float16* QlT = QhT + (size_t)M_ROWS * DKK;
    _Float16* KhT = QlT + (size_t)M_ROWS * DKK;
    _Float16* KlT = KhT + (size_t)N_KEYS * DKK;
    u64t* plist   = (u64t*)(KlT + (size_t)N_KEYS * DKK);

    norm_split_kernel<<<(M_ROWS + N_KEYS) / 4, 256, 0, stream>>>(q, keys, QhT, QlT, KhT, KlT);
    dim3 g2(MBLKS, NSPLIT, 1);
    pass1_kernel<<<g2, 512, 0, stream>>>(QhT, KhT, plist);
    pass2_kernel<<<M_ROWS, 256, 0, stream>>>(plist, QhT, QlT, KhT, KlT, values,
                                             out_agg, out_attn, out_idx);
  } else {
    float* ws     = (float*)d_ws;
    float* qn     = ws;
    float* kinv   = qn + (size_t)M_ROWS * DKK;
    float* pscore = kinv + N_KEYS;
    int*   pidx   = (int*)(pscore + (size_t)M_ROWS * NSPLIT * KTOP);

    norm_kernel<<<(M_ROWS + N_KEYS) / 4, 256, 0, stream>>>(q, keys, qn, kinv);
    dim3 g2(NSPLIT, M_ROWS / QB, 1);
    score_topk_kernel<<<g2, 256, 0, stream>>>(qn, keys, kinv, pscore, pidx);
    merge_kernel<<<M_ROWS, 256, 0, stream>>>(pscore, pidx, values, out_agg, out_attn, out_idx);
  }
}